// Round 5
// baseline (776.168 us; speedup 1.0000x reference)
//
#include <hip/hip_runtime.h>

// CRF log-likelihood, round 5: single-wave MFMA scan + ds_bpermute transpose.
// K1 (crf_score): unary+binary scores -> d_ws (unchanged, ~5us).
// K2 (crf_scan): 16 blocks x 192 threads (3 waves), 16 batches/block.
//   W0 (consumer): full 128x128 matvec/step: 32x mfma_f32_16x16x32_bf16
//     (A = E^T static in VGPRs: 8 m-tiles x 4 k-chunks). D->B transpose done
//     IN-WAVE via 8 cndmask + 16 ds_bpermute (no LDS round-trip, no barrier
//     dependency). q kept UNNORMALIZED in bf16 (f32 exponent range); renorm
//     by c=rcp(S0) only every 4 steps, exact scale in Dacc (log2).
//   W1/W2 (producers): u_t = exp(in[t]) -> 4-slot LDS ring, 3 steps ahead,
//     with global loads prefetched one iteration ahead (HBM latency covered).
//   Barrier = s_waitcnt lgkmcnt(0); s_barrier (no vmcnt drain).
// Layout identities (verified by round-3/4 absmax=0 kernels):
//   A(m,k): lane m=lane&15, k=quad*8+jj per 32-chunk.
//   B(k,n): lane n=lane&15, k=kc*32+quad*8+jj.
//   D(m,n): n=lane&15, m=mt*16+quad*4+reg.
// bpermute map (target word (kc,w) at quad): src reg ws=4kc+2*(quad>>1)+(w&1),
//   src lane = ((2*quad+(w>>1))&3)*16+bl  ->  idx0=((quad&1)*32+bl)*4,
//   idx1=idx0+64; reg select by (lane<32).

#define B_   256
#define LL   1024
#define TT   128
#define NBAT 16
#define NBLK (B_ / NBAT)
#define L2E  1.4426950408889634f
#define LN2f 0.6931471805599453f
#define UST  132            // floats per u row (128 + 4 pad)

typedef __attribute__((ext_vector_type(8))) short bf16x8;
typedef __attribute__((ext_vector_type(4))) float f32x4;

union bfrw { unsigned w[4]; bf16x8 v; };

__device__ __forceinline__ unsigned bfround(float x) {   // RNE bf16 bits in [31:16]
    unsigned u = __float_as_uint(x);
    return u + 0x7fffu + ((u >> 16) & 1u);
}
__device__ __forceinline__ unsigned rnd16(float x) {     // cheap half-up rounding
    return __float_as_uint(x) + 0x8000u;
}
__device__ __forceinline__ int bperm(int idx, float v) {
    return __builtin_amdgcn_ds_bpermute(idx, __float_as_int(v));
}
__device__ __forceinline__ void lds_barrier() {
    asm volatile("s_waitcnt lgkmcnt(0)\n\ts_barrier" ::: "memory");
}

__global__ void crf_score(const float* __restrict__ inputs,
                          const int*   __restrict__ tags,
                          const int*   __restrict__ slens,
                          const float* __restrict__ trans,
                          float* __restrict__ scorebuf) {
    const int b = blockIdx.x, tid = threadIdx.x;
    const int lane = tid & 63, wid = tid >> 6;
    __shared__ float wsc[4];
    const int slen = slens[b];
    const float* inb  = inputs + (size_t)b * LL * TT;
    const int*   tagb = tags + b * LL;
    float sc = 0.f;
    for (int t = tid; t < slen; t += 256) {
        int tg = tagb[t];
        float v = inb[(size_t)t * TT + tg];
        if (t >= 1) v += trans[tagb[t - 1] * TT + tg];
        sc += v;
    }
    #pragma unroll
    for (int off = 32; off > 0; off >>= 1) sc += __shfl_xor(sc, off, 64);
    if (lane == 0) wsc[wid] = sc;
    __syncthreads();
    if (tid == 0) scorebuf[b] = wsc[0] + wsc[1] + wsc[2] + wsc[3];
}

__launch_bounds__(192, 1)
__global__ void crf_scan(const float* __restrict__ inputs,
                         const int*   __restrict__ slens,
                         const float* __restrict__ trans,
                         const float* __restrict__ scorebuf,
                         float* __restrict__ out) {
    const int tid  = threadIdx.x;
    const int lane = tid & 63;
    const int wid  = __builtin_amdgcn_readfirstlane(tid >> 6);
    const int quad = lane >> 4;
    const int bl   = lane & 15;
    const int bb0  = blockIdx.x * NBAT;

    __shared__ __align__(16) float ubuf[4][NBAT][UST];
    __shared__ float fin[NBAT];
    __shared__ float dcap[NBAT];

    // tfin per batch (lane's bl), block-uniform tmax (all waves identically)
    const int sl = slens[bb0 + bl];
    int tfin = sl - 1; if (tfin < 1) tfin = 1;
    int tmax = tfin;
    #pragma unroll
    for (int off = 1; off < 16; off <<= 1) {
        int o = __shfl_xor(tmax, off, 64);
        tmax = o > tmax ? o : tmax;
    }
    tmax = __builtin_amdgcn_readfirstlane(tmax);

    if (wid == 0) {
        // ---------------- consumer ----------------
        // A fragments: af[mt][kc][jj] = bf16(exp(trans[k][j])), j=mt*16+bl,
        // k = kc*32 + quad*8 + jj
        bf16x8 af[8][4];
        #pragma unroll
        for (int mt = 0; mt < 8; ++mt) {
            const int j = mt * 16 + bl;
            #pragma unroll
            for (int kc = 0; kc < 4; ++kc) {
                #pragma unroll
                for (int jj = 0; jj < 8; ++jj) {
                    int k = kc * 32 + quad * 8 + jj;
                    float ev = __builtin_amdgcn_exp2f(trans[k * TT + j] * L2E);
                    af[mt][kc][jj] = (short)(bfround(ev) >> 16);
                }
            }
        }

        // q0 packed words: P[mt*2+p] holds j = mt*16+quad*4+2p (lo), +1 (hi)
        unsigned P[16];
        {
            const float* p0 = inputs + (size_t)(bb0 + bl) * LL * TT + quad * 4;
            #pragma unroll
            for (int mt = 0; mt < 8; ++mt) {
                float4 v = *(const float4*)(p0 + mt * 16);
                float4 e;
                e.x = __builtin_amdgcn_exp2f(v.x * L2E);
                e.y = __builtin_amdgcn_exp2f(v.y * L2E);
                e.z = __builtin_amdgcn_exp2f(v.z * L2E);
                e.w = __builtin_amdgcn_exp2f(v.w * L2E);
                P[mt*2+0] = __builtin_amdgcn_perm(bfround(e.y), bfround(e.x), 0x07060302);
                P[mt*2+1] = __builtin_amdgcn_perm(bfround(e.w), bfround(e.z), 0x07060302);
            }
        }

        const int idx0 = ((quad & 1) * 32 + bl) * 4;
        const int idx1 = idx0 + 64;
        const bool lo32 = (lane < 32);
        float Dacc = 0.f;

        lds_barrier();   // producers filled u slots 1..3

        for (int t = 1; t <= tmax; ++t) {
            // ---- B-build: in-wave transpose via cndmask + bpermute ----
            bfrw bfr[4];
            #pragma unroll
            for (int kc = 0; kc < 4; ++kc) {
                float s0 = __uint_as_float(lo32 ? P[4*kc+0] : P[4*kc+2]);
                float s1 = __uint_as_float(lo32 ? P[4*kc+1] : P[4*kc+3]);
                bfr[kc].w[0] = (unsigned)bperm(idx0, s0);
                bfr[kc].w[1] = (unsigned)bperm(idx0, s1);
                bfr[kc].w[2] = (unsigned)bperm(idx1, s0);
                bfr[kc].w[3] = (unsigned)bperm(idx1, s1);
            }
            // ---- u_t from ring (issued after bperms; used ~300cyc later) ----
            const float* ub = &ubuf[t & 3][bl][quad * 4];
            float4 uu[8];
            #pragma unroll
            for (int mt = 0; mt < 8; ++mt)
                uu[mt] = *(const float4*)(ub + mt * 16);

            // ---- 32 MFMA: 8 independent depth-4 chains ----
            f32x4 acc[8];
            #pragma unroll
            for (int mt = 0; mt < 8; ++mt) acc[mt] = (f32x4){0.f,0.f,0.f,0.f};
            #pragma unroll
            for (int kc = 0; kc < 4; ++kc) {
                #pragma unroll
                for (int mt = 0; mt < 8; ++mt)
                    acc[mt] = __builtin_amdgcn_mfma_f32_16x16x32_bf16(
                        af[mt][kc], bfr[kc].v, acc[mt], 0, 0, 0);
            }

            // ---- epilogue: q = u * s, renorm every 4 steps ----
            float qv[32];
            #pragma unroll
            for (int mt = 0; mt < 8; ++mt) {
                qv[4*mt+0] = uu[mt].x * acc[mt][0];
                qv[4*mt+1] = uu[mt].y * acc[mt][1];
                qv[4*mt+2] = uu[mt].z * acc[mt][2];
                qv[4*mt+3] = uu[mt].w * acc[mt][3];
            }
            if ((t & 3) == 0) {
                // S0 = s[j=0] lives in acc[0][0] on lane bl (quad 0)
                float s0b = __int_as_float(bperm(4 * bl, acc[0][0]));
                float c = __builtin_amdgcn_rcpf(s0b);
                Dacc += __builtin_amdgcn_logf(s0b);     // v_log_f32 = log2
                #pragma unroll
                for (int k = 0; k < 32; ++k) qv[k] *= c;
            }
            #pragma unroll
            for (int mt = 0; mt < 8; ++mt) {
                P[mt*2+0] = __builtin_amdgcn_perm(rnd16(qv[4*mt+1]), rnd16(qv[4*mt+0]), 0x07060302);
                P[mt*2+1] = __builtin_amdgcn_perm(rnd16(qv[4*mt+3]), rnd16(qv[4*mt+2]), 0x07060302);
            }

            // ---- rare per-batch capture at t == tfin_b ----
            bool cap = (tfin == t);
            if (__any(cap)) {
                float ps = 0.f;
                #pragma unroll
                for (int k = 0; k < 32; ++k) ps += qv[k];
                ps += __shfl_xor(ps, 16, 64);
                ps += __shfl_xor(ps, 32, 64);
                if (cap && quad == 0) { fin[bl] = ps; dcap[bl] = Dacc; }
            }
            lds_barrier();
        }

        if (lane < 16) {
            float logZ = LN2f * (__builtin_amdgcn_logf(fin[lane]) + dcap[lane]);
            out[bb0 + lane] = scorebuf[bb0 + lane] - logZ;
        }
    } else {
        // ---------------- producers (wid 1,2) ----------------
        const int pw = wid - 1;                 // j-half
        const int pb = lane >> 2;               // batch
        const int jb = pw * 64 + (lane & 3) * 16;
        const float* ps = inputs + (size_t)(bb0 + pb) * LL * TT + jb;

        // prefill u for t = 1..3
        for (int s = 1; s <= 3; ++s) {
            #pragma unroll
            for (int c = 0; c < 4; ++c) {
                float4 v = *(const float4*)(ps + (size_t)s * TT + 4 * c);
                float4 e;
                e.x = __builtin_amdgcn_exp2f(v.x * L2E);
                e.y = __builtin_amdgcn_exp2f(v.y * L2E);
                e.z = __builtin_amdgcn_exp2f(v.z * L2E);
                e.w = __builtin_amdgcn_exp2f(v.w * L2E);
                *(float4*)&ubuf[s][pb][jb + 4 * c] = e;
            }
        }
        // prefetch regs for t = 4
        float4 fr[4];
        #pragma unroll
        for (int c = 0; c < 4; ++c)
            fr[c] = *(const float4*)(ps + (size_t)4 * TT + 4 * c);

        lds_barrier();

        for (int t = 1; t <= tmax; ++t) {
            const int slot = (t + 3) & 3;
            #pragma unroll
            for (int c = 0; c < 4; ++c) {
                float4 v = fr[c];
                float4 e;
                e.x = __builtin_amdgcn_exp2f(v.x * L2E);
                e.y = __builtin_amdgcn_exp2f(v.y * L2E);
                e.z = __builtin_amdgcn_exp2f(v.z * L2E);
                e.w = __builtin_amdgcn_exp2f(v.w * L2E);
                *(float4*)&ubuf[slot][pb][jb + 4 * c] = e;
            }
            int tp = t + 4; if (tp > LL - 1) tp = LL - 1;
            #pragma unroll
            for (int c = 0; c < 4; ++c)
                fr[c] = *(const float4*)(ps + (size_t)tp * TT + 4 * c);
            lds_barrier();
        }
    }
}

extern "C" void kernel_launch(void* const* d_in, const int* in_sizes, int n_in,
                              void* d_out, int out_size, void* d_ws, size_t ws_size,
                              hipStream_t stream) {
    const float* inputs = (const float*)d_in[0];
    const int*   tags   = (const int*)d_in[1];
    const int*   slens  = (const int*)d_in[2];
    const float* trans  = (const float*)d_in[3];
    float* out      = (float*)d_out;
    float* scorebuf = (float*)d_ws;

    crf_score<<<B_, 256, 0, stream>>>(inputs, tags, slens, trans, scorebuf);
    crf_scan<<<NBLK, 192, 0, stream>>>(inputs, slens, trans, scorebuf, out);
}

// Round 6
// 430.742 us; speedup vs baseline: 1.8019x; 1.8019x over previous
//
#include <hip/hip_runtime.h>

// CRF log-likelihood, round 6: fwd+bwd split scan (chain 1023 -> ~545) with
// slen-sorted batch grouping, MFMA-batched linear-domain steps, conflict-free
// segment LDS exchange.
//
// K1 crf_score: unary+binary scores -> ws.scorebuf (per ORIGINAL batch).
// K2 crf_scan: 32 blocks x 256 thr. Every block bitonic-sorts (slen,b) keys
//   (deterministic, identical in all blocks). Block g<16: FORWARD scan of
//   sorted ranks 16g..16g+15, t=1..cmax (cb=tfin>>1), captures q_cb -> qcap.
//   Block 16+g: BACKWARD scan r_{t-1}=E(u_t.*r_t) from r_tfin=1 (injected
//   per-batch when t-1==tfin), t=tb0..cmin+1, captures r_cb -> rcap.
//   Per step: 8x mfma_f32_16x16x32_bf16 per wave (4 waves, all SIMDs),
//   q/w exchanged via LDS segments: wave w lane(bl,quad) writes ONE b128 at
//   seg=4w+quad, reads 4 b128 at seg=4c+quad; A-fragments built with the
//   matching k-permutation k(seg,jj)=32(seg>>2)+16(jj>>2)+4(seg&3)+(jj&3)
//   (any consistent A/B k-permutation is valid for MFMA). Bank pattern
//   4*(bl+quad)+16c: conflict-free. u from a depth-4 register ring (t+-4).
//   Lag-1 renorm c=rcp(S0_prev), exact scale in Dacc (log2); barriers are
//   s_waitcnt lgkmcnt(0); s_barrier (no vmcnt drain).
// K3 crf_comb: per sorted rank: logZ=ln2*(log2(dot(qcap,rcap))+Dq+Dr);
//   out[orig] = score[orig] - logZ.

#define B_   256
#define LL   1024
#define TT   128
#define NBLK 16
#define L2E  1.4426950408889634f
#define LN2f 0.6931471805599453f

typedef __attribute__((ext_vector_type(8))) short bf16x8;
typedef __attribute__((ext_vector_type(4))) float f32x4;
union bfrw { unsigned w[4]; bf16x8 v; };

__device__ __forceinline__ unsigned bfround(float x) {   // RNE bf16 bits in [31:16]
    unsigned u = __float_as_uint(x);
    return u + 0x7fffu + ((u >> 16) & 1u);
}
__device__ __forceinline__ void lds_barrier() {
    asm volatile("s_waitcnt lgkmcnt(0)\n\ts_barrier" ::: "memory");
}

__global__ void crf_score(const float* __restrict__ inputs,
                          const int*   __restrict__ tags,
                          const int*   __restrict__ slens,
                          const float* __restrict__ trans,
                          float* __restrict__ scorebuf) {
    const int b = blockIdx.x, tid = threadIdx.x;
    const int lane = tid & 63, wid = tid >> 6;
    __shared__ float wsc[4];
    const int slen = slens[b];
    const float* inb  = inputs + (size_t)b * LL * TT;
    const int*   tagb = tags + b * LL;
    float sc = 0.f;
    for (int t = tid; t < slen; t += 256) {
        int tg = tagb[t];
        float v = inb[(size_t)t * TT + tg];
        if (t >= 1) v += trans[tagb[t - 1] * TT + tg];
        sc += v;
    }
    #pragma unroll
    for (int off = 32; off > 0; off >>= 1) sc += __shfl_xor(sc, off, 64);
    if (lane == 0) wsc[wid] = sc;
    __syncthreads();
    if (tid == 0) scorebuf[b] = wsc[0] + wsc[1] + wsc[2] + wsc[3];
}

template<bool FWD, int PH>
__device__ __forceinline__ void phase(int t, float& Dacc, float4 (&up)[4][2],
                                      const bf16x8 (&af)[2][4],
                                      short* qls, float* sb, const float* pu,
                                      float* __restrict__ qcap, float* __restrict__ rcap,
                                      float* __restrict__ dqv, float* __restrict__ drv,
                                      int cb, int tfin, int rank,
                                      int wid, int quad, int bl)
{
    constexpr int CUR  = PH & 1;
    constexpr int NXT  = CUR ^ 1;
    constexpr int SLOT = FWD ? ((1 + PH) & 3) : ((3 - PH) & 3);

    // B fragments: 4x ds_read_b128, conflict-free segment layout
    bfrw bfr[4];
    #pragma unroll
    for (int c = 0; c < 4; ++c)
        bfr[c].v = *(const bf16x8*)(qls + CUR * (16 * 136) + bl * 136 + (4 * c + quad) * 8);
    float sprev = sb[CUR * 16 + bl];

    // u from register ring (fwd: u_t; bwd: u_{t-1})
    float ex[8];
    #pragma unroll
    for (int mt = 0; mt < 2; ++mt) {
        float4 v = up[SLOT][mt];
        ex[4*mt+0] = __builtin_amdgcn_exp2f(v.x * L2E);
        ex[4*mt+1] = __builtin_amdgcn_exp2f(v.y * L2E);
        ex[4*mt+2] = __builtin_amdgcn_exp2f(v.z * L2E);
        ex[4*mt+3] = __builtin_amdgcn_exp2f(v.w * L2E);
    }
    // prefetch into the freed slot (consumed 4 steps later)
    {
        int tp = FWD ? (t + 4) : (t - 5);
        tp = tp < 0 ? 0 : (tp > LL - 1 ? LL - 1 : tp);
        #pragma unroll
        for (int mt = 0; mt < 2; ++mt)
            up[SLOT][mt] = *(const float4*)(pu + (size_t)tp * TT + mt * 16);
    }

    // 8 MFMA: two independent depth-4 chains
    f32x4 a0 = {0.f,0.f,0.f,0.f}, a1 = {0.f,0.f,0.f,0.f};
    #pragma unroll
    for (int c = 0; c < 4; ++c) {
        a0 = __builtin_amdgcn_mfma_f32_16x16x32_bf16(af[0][c], bfr[c].v, a0, 0, 0, 0);
        a1 = __builtin_amdgcn_mfma_f32_16x16x32_bf16(af[1][c], bfr[c].v, a1, 0, 0, 0);
    }

    float ci = __builtin_amdgcn_rcpf(sprev);
    Dacc += __builtin_amdgcn_logf(sprev);          // v_log_f32 = log2
    float rv[8];
    #pragma unroll
    for (int r = 0; r < 4; ++r) { rv[r] = ci * a0[r]; rv[4 + r] = ci * a1[r]; }

    if (!FWD) {
        bool cap = (cb == t - 1);
        if (__any(cap)) {
            if (cap) {
                float4 s0 = {rv[0], rv[1], rv[2], rv[3]};
                float4 s1 = {rv[4], rv[5], rv[6], rv[7]};
                *(float4*)(rcap + rank * TT + wid * 32 + quad * 4) = s0;
                *(float4*)(rcap + rank * TT + wid * 32 + 16 + quad * 4) = s1;
                if (wid == 0 && quad == 0) drv[rank] = Dacc;
            }
        }
        bool inj = (tfin == t - 1);
        #pragma unroll
        for (int k = 0; k < 8; ++k) rv[k] = inj ? 1.0f : rv[k];
        Dacc = inj ? 0.0f : Dacc;
    }

    float ov[8];
    #pragma unroll
    for (int k = 0; k < 8; ++k) ov[k] = ex[k] * rv[k];

    if (FWD) {
        bool cap = (cb == t);
        if (__any(cap)) {
            if (cap) {
                float4 s0 = {ov[0], ov[1], ov[2], ov[3]};
                float4 s1 = {ov[4], ov[5], ov[6], ov[7]};
                *(float4*)(qcap + rank * TT + wid * 32 + quad * 4) = s0;
                *(float4*)(qcap + rank * TT + wid * 32 + 16 + quad * 4) = s1;
                if (wid == 0 && quad == 0) dqv[rank] = Dacc;
            }
        }
    }

    if (wid == 0 && quad == 0) sb[NXT * 16 + bl] = a0[0];   // raw S0 (j=0)

    bfrw pk;
    pk.w[0] = __builtin_amdgcn_perm(bfround(ov[1]), bfround(ov[0]), 0x07060302);
    pk.w[1] = __builtin_amdgcn_perm(bfround(ov[3]), bfround(ov[2]), 0x07060302);
    pk.w[2] = __builtin_amdgcn_perm(bfround(ov[5]), bfround(ov[4]), 0x07060302);
    pk.w[3] = __builtin_amdgcn_perm(bfround(ov[7]), bfround(ov[6]), 0x07060302);
    *(bf16x8*)(qls + NXT * (16 * 136) + bl * 136 + (4 * wid + quad) * 8) = pk.v;

    lds_barrier();
}

__launch_bounds__(256, 1)
__global__ void crf_scan(const float* __restrict__ inputs,
                         const int*   __restrict__ slens,
                         const float* __restrict__ trans,
                         float* __restrict__ qcap, float* __restrict__ rcap,
                         float* __restrict__ dqv,  float* __restrict__ drv,
                         int* __restrict__ perm)
{
    __shared__ __align__(16) short qls[2 * 16 * 136];
    __shared__ float sb[2 * 16];
    __shared__ int keys[B_];

    const int tid  = threadIdx.x;
    const int lane = tid & 63;
    const int wid  = __builtin_amdgcn_readfirstlane(tid >> 6);
    const int quad = lane >> 4;
    const int bl   = lane & 15;
    const bool isf = (blockIdx.x < NBLK);
    const int g    = isf ? blockIdx.x : blockIdx.x - NBLK;

    // deterministic bitonic sort of (slen, batch) keys — identical in all blocks
    keys[tid] = slens[tid] * 256 + tid;
    __syncthreads();
    for (int k = 2; k <= B_; k <<= 1) {
        for (int s = k >> 1; s > 0; s >>= 1) {
            int ixj = tid ^ s;
            if (ixj > tid) {
                int a = keys[tid], b2 = keys[ixj];
                bool asc = ((tid & k) == 0);
                if ((a > b2) == asc) { keys[tid] = b2; keys[ixj] = a; }
            }
            __syncthreads();
        }
    }
    if (isf && tid < 16) perm[g * 16 + tid] = keys[g * 16 + tid] & 255;

    const int key = keys[g * 16 + bl];
    const int ob  = key & 255;
    const int sl  = key >> 8;
    int tfin = sl - 1; if (tfin < 1) tfin = 1;
    const int cb = tfin >> 1;

    int cmax = cb, cmin = cb, tmax = tfin;
    #pragma unroll
    for (int o = 1; o < 16; o <<= 1) {
        int a = __shfl_xor(cmax, o, 16); cmax = a > cmax ? a : cmax;
        int b2 = __shfl_xor(cmin, o, 16); cmin = b2 < cmin ? b2 : cmin;
        int c2 = __shfl_xor(tmax, o, 16); tmax = c2 > tmax ? c2 : tmax;
    }
    cmax = __builtin_amdgcn_readfirstlane(cmax);
    cmin = __builtin_amdgcn_readfirstlane(cmin);
    tmax = __builtin_amdgcn_readfirstlane(tmax);

    // A fragments with the segment k-permutation:
    // k(c,quad,jj) = 32c + 16*(jj>>2) + 4*quad + (jj&3); j = wid*32+mt*16+bl
    bf16x8 af[2][4];
    #pragma unroll
    for (int mt = 0; mt < 2; ++mt) {
        const int j = wid * 32 + mt * 16 + bl;
        #pragma unroll
        for (int c = 0; c < 4; ++c) {
            #pragma unroll
            for (int jj = 0; jj < 8; ++jj) {
                int k = 32 * c + 16 * (jj >> 2) + 4 * quad + (jj & 3);
                int idx = isf ? (k * TT + j) : (j * TT + k);
                float ev = __builtin_amdgcn_exp2f(trans[idx] * L2E);
                af[mt][c][jj] = (short)(bfround(ev) >> 16);
            }
        }
    }

    const float* pu = inputs + (size_t)ob * LL * TT + wid * 32 + quad * 4;
    const int rank = g * 16 + bl;
    float Dacc = 0.f;
    float4 up[4][2];

    if (tid < 16) sb[tid] = 1.0f;

    if (isf) {
        // init q0 = exp(in[0][j]) -> qls buf0; early-capture cb==0
        float q0[8];
        #pragma unroll
        for (int mt = 0; mt < 2; ++mt) {
            float4 v = *(const float4*)(pu + mt * 16);
            q0[4*mt+0] = __builtin_amdgcn_exp2f(v.x * L2E);
            q0[4*mt+1] = __builtin_amdgcn_exp2f(v.y * L2E);
            q0[4*mt+2] = __builtin_amdgcn_exp2f(v.z * L2E);
            q0[4*mt+3] = __builtin_amdgcn_exp2f(v.w * L2E);
        }
        bfrw pk;
        pk.w[0] = __builtin_amdgcn_perm(bfround(q0[1]), bfround(q0[0]), 0x07060302);
        pk.w[1] = __builtin_amdgcn_perm(bfround(q0[3]), bfround(q0[2]), 0x07060302);
        pk.w[2] = __builtin_amdgcn_perm(bfround(q0[5]), bfround(q0[4]), 0x07060302);
        pk.w[3] = __builtin_amdgcn_perm(bfround(q0[7]), bfround(q0[6]), 0x07060302);
        *(bf16x8*)(qls + bl * 136 + (4 * wid + quad) * 8) = pk.v;
        if (cb == 0) {
            float4 s0 = {q0[0], q0[1], q0[2], q0[3]};
            float4 s1 = {q0[4], q0[5], q0[6], q0[7]};
            *(float4*)(qcap + rank * TT + wid * 32 + quad * 4) = s0;
            *(float4*)(qcap + rank * TT + wid * 32 + 16 + quad * 4) = s1;
            if (wid == 0 && quad == 0) dqv[rank] = 0.f;
        }
        #pragma unroll
        for (int s = 1; s <= 4; ++s) {
            #pragma unroll
            for (int mt = 0; mt < 2; ++mt)
                up[s & 3][mt] = *(const float4*)(pu + (size_t)s * TT + mt * 16);
        }
        __syncthreads();

        for (int tb = 1; tb <= cmax; tb += 4) {
            phase<true,0>(tb+0, Dacc, up, af, qls, sb, pu, qcap, rcap, dqv, drv, cb, tfin, rank, wid, quad, bl);
            phase<true,1>(tb+1, Dacc, up, af, qls, sb, pu, qcap, rcap, dqv, drv, cb, tfin, rank, wid, quad, bl);
            phase<true,2>(tb+2, Dacc, up, af, qls, sb, pu, qcap, rcap, dqv, drv, cb, tfin, rank, wid, quad, bl);
            phase<true,3>(tb+3, Dacc, up, af, qls, sb, pu, qcap, rcap, dqv, drv, cb, tfin, rank, wid, quad, bl);
        }
    } else {
        // init w = 1.0 (every batch re-injected at t-1==tfin)
        bfrw pk;
        pk.w[0] = pk.w[1] = pk.w[2] = pk.w[3] = 0x3F803F80u;
        *(bf16x8*)(qls + bl * 136 + (4 * wid + quad) * 8) = pk.v;

        const int tb0 = (tmax + 4) & ~3;   // >= tmax+1, == 0 mod 4
        #pragma unroll
        for (int ph = 0; ph < 4; ++ph) {
            int ui = tb0 - 1 - ph;
            ui = ui > LL - 1 ? LL - 1 : (ui < 0 ? 0 : ui);
            #pragma unroll
            for (int mt = 0; mt < 2; ++mt)
                up[(3 - ph) & 3][mt] = *(const float4*)(pu + (size_t)ui * TT + mt * 16);
        }
        __syncthreads();

        for (int tb = tb0; tb > cmin; tb -= 4) {
            phase<false,0>(tb-0, Dacc, up, af, qls, sb, pu, qcap, rcap, dqv, drv, cb, tfin, rank, wid, quad, bl);
            phase<false,1>(tb-1, Dacc, up, af, qls, sb, pu, qcap, rcap, dqv, drv, cb, tfin, rank, wid, quad, bl);
            phase<false,2>(tb-2, Dacc, up, af, qls, sb, pu, qcap, rcap, dqv, drv, cb, tfin, rank, wid, quad, bl);
            phase<false,3>(tb-3, Dacc, up, af, qls, sb, pu, qcap, rcap, dqv, drv, cb, tfin, rank, wid, quad, bl);
        }
    }
}

__global__ void crf_comb(const float* __restrict__ qcap, const float* __restrict__ rcap,
                         const float* __restrict__ dqv, const float* __restrict__ drv,
                         const int* __restrict__ perm, const float* __restrict__ scorebuf,
                         float* __restrict__ out) {
    const int tid = threadIdx.x;
    const int r16 = tid >> 4, part = tid & 15;
    const int rank = blockIdx.x * 16 + r16;
    const float* qc = qcap + rank * TT + part * 8;
    const float* rc = rcap + rank * TT + part * 8;
    float4 a0 = *(const float4*)(qc);
    float4 a1 = *(const float4*)(qc + 4);
    float4 b0 = *(const float4*)(rc);
    float4 b1 = *(const float4*)(rc + 4);
    float s = a0.x*b0.x + a0.y*b0.y + a0.z*b0.z + a0.w*b0.w
            + a1.x*b1.x + a1.y*b1.y + a1.z*b1.z + a1.w*b1.w;
    #pragma unroll
    for (int o = 1; o < 16; o <<= 1) s += __shfl_xor(s, o, 16);
    if (part == 0) {
        int ob = perm[rank];
        float logZ = LN2f * (__builtin_amdgcn_logf(s) + dqv[rank] + drv[rank]);
        out[ob] = scorebuf[ob] - logZ;
    }
}

extern "C" void kernel_launch(void* const* d_in, const int* in_sizes, int n_in,
                              void* d_out, int out_size, void* d_ws, size_t ws_size,
                              hipStream_t stream) {
    const float* inputs = (const float*)d_in[0];
    const int*   tags   = (const int*)d_in[1];
    const int*   slens  = (const int*)d_in[2];
    const float* trans  = (const float*)d_in[3];
    float* out = (float*)d_out;

    float* qcap = (float*)d_ws;            // 256*128 f32
    float* rcap = qcap + 32768;            // 256*128 f32
    float* dqv  = rcap + 32768;            // 256
    float* drv  = dqv + 256;               // 256
    int*   perm = (int*)(drv + 256);       // 256
    float* scorebuf = (float*)(perm + 256);// 256   (total ~266 KB)

    crf_score<<<B_, 256, 0, stream>>>(inputs, tags, slens, trans, scorebuf);
    crf_scan<<<2 * NBLK, 256, 0, stream>>>(inputs, slens, trans, qcap, rcap, dqv, drv, perm);
    crf_comb<<<NBLK, 256, 0, stream>>>(qcap, rcap, dqv, drv, perm, scorebuf, out);
}

// Round 7
// 412.513 us; speedup vs baseline: 1.8816x; 1.0442x over previous
//
#include <hip/hip_runtime.h>

// CRF log-likelihood, round 7: balanced fwd/bwd split scan, depth-2 MFMA
// chains, cvt_pk_bf16_f32 pack, score folded into the scan launch.
//
// crf_scan grid = 96 blocks x 256 thr:
//   blocks 0..15  : FORWARD scan, sorted ranks 16g..16g+15, t=1..cmax,
//                   captures q_cb -> qcap (cb = min(tfin, C), C=(tmax+4)>>1).
//   blocks 16..31 : BACKWARD scan r_{t-1}=E(u_t.*r_t) from r_tfin=1,
//                   t=tb0..cmin+1, captures r_cb -> rcap. cb==tfin batches
//                   capture ones/Dr=0 at init.
//   blocks 32..95 : unary+binary scores (4 batches each) -> scorebuf,
//                   concurrent with the scan (latency-bound scan leaves CUs idle).
// Per scan step/wave: 4 ds_read_b128 (segment layout, round-6-verified k-perm),
// 8 mfma_f32_16x16x32_bf16 into 4 accumulators (depth-2 chains) + f32x4 merge,
// lag-1 renorm c=rcp(S0_prev) with exact Dacc (log2), u from depth-4 register
// ring, pack via v_cvt_pk_bf16_f32 (RNE) if available else bfround+perm,
// barrier = s_waitcnt lgkmcnt(0); s_barrier.
// crf_comb: logZ = ln2*(log2(dot(qcap,rcap)) + Dq + Dr); out = score - logZ.

#define B_   256
#define LL   1024
#define TT   128
#define NBLK 16
#define L2E  1.4426950408889634f
#define LN2f 0.6931471805599453f

typedef __attribute__((ext_vector_type(8))) short bf16x8;
typedef __attribute__((ext_vector_type(4))) float f32x4;
union bfrw { unsigned w[4]; bf16x8 v; };

__device__ __forceinline__ unsigned bfround(float x) {   // RNE bf16 bits in [31:16]
    unsigned u = __float_as_uint(x);
    return u + 0x7fffu + ((u >> 16) & 1u);
}
__device__ __forceinline__ unsigned pack2(float lo, float hi) {  // [hi|lo] bf16 pair
#if __has_builtin(__builtin_amdgcn_cvt_pk_bf16_f32)
    auto p = __builtin_amdgcn_cvt_pk_bf16_f32(lo, hi);
    unsigned w; __builtin_memcpy(&w, &p, 4); return w;
#else
    return __builtin_amdgcn_perm(bfround(hi), bfround(lo), 0x07060302);
#endif
}
__device__ __forceinline__ void lds_barrier() {
    asm volatile("s_waitcnt lgkmcnt(0)\n\ts_barrier" ::: "memory");
}

template<bool FWD, int PH>
__device__ __forceinline__ void phase(int t, float& Dacc, float4 (&up)[4][2],
                                      const bf16x8 (&af)[2][4],
                                      short* qls, float* sb, const float* pu,
                                      float* __restrict__ qcap, float* __restrict__ rcap,
                                      float* __restrict__ dqv, float* __restrict__ drv,
                                      int cb, int tfin, int rank,
                                      int wid, int quad, int bl)
{
    constexpr int CUR  = PH & 1;
    constexpr int NXT  = CUR ^ 1;
    constexpr int SLOT = FWD ? ((1 + PH) & 3) : ((3 - PH) & 3);

    // ---- head: B fragments + S0_prev ----
    bfrw bfr[4];
    #pragma unroll
    for (int c = 0; c < 4; ++c)
        bfr[c].v = *(const bf16x8*)(qls + CUR * (16 * 136) + bl * 136 + (4 * c + quad) * 8);
    float sprev = sb[CUR * 16 + bl];
    float ci = __builtin_amdgcn_rcpf(sprev);

    // ---- 8 MFMA: 4 accumulators, two depth-2 chains per m-tile ----
    f32x4 ae0 = {0.f,0.f,0.f,0.f}, ao0 = {0.f,0.f,0.f,0.f};
    f32x4 ae1 = {0.f,0.f,0.f,0.f}, ao1 = {0.f,0.f,0.f,0.f};
    ae0 = __builtin_amdgcn_mfma_f32_16x16x32_bf16(af[0][0], bfr[0].v, ae0, 0, 0, 0);
    ae1 = __builtin_amdgcn_mfma_f32_16x16x32_bf16(af[1][0], bfr[0].v, ae1, 0, 0, 0);
    ao0 = __builtin_amdgcn_mfma_f32_16x16x32_bf16(af[0][1], bfr[1].v, ao0, 0, 0, 0);
    ao1 = __builtin_amdgcn_mfma_f32_16x16x32_bf16(af[1][1], bfr[1].v, ao1, 0, 0, 0);
    ae0 = __builtin_amdgcn_mfma_f32_16x16x32_bf16(af[0][2], bfr[2].v, ae0, 0, 0, 0);
    ae1 = __builtin_amdgcn_mfma_f32_16x16x32_bf16(af[1][2], bfr[2].v, ae1, 0, 0, 0);
    ao0 = __builtin_amdgcn_mfma_f32_16x16x32_bf16(af[0][3], bfr[3].v, ao0, 0, 0, 0);
    ao1 = __builtin_amdgcn_mfma_f32_16x16x32_bf16(af[1][3], bfr[3].v, ao1, 0, 0, 0);

    // u_t (fwd) / u_{t-1} (bwd) from ring; exp issues under MFMA latency
    float ex[8];
    #pragma unroll
    for (int mt = 0; mt < 2; ++mt) {
        float4 v = up[SLOT][mt];
        ex[4*mt+0] = __builtin_amdgcn_exp2f(v.x * L2E);
        ex[4*mt+1] = __builtin_amdgcn_exp2f(v.y * L2E);
        ex[4*mt+2] = __builtin_amdgcn_exp2f(v.z * L2E);
        ex[4*mt+3] = __builtin_amdgcn_exp2f(v.w * L2E);
    }
    {   // prefetch into the freed slot (consumed 4 steps later)
        int tp = FWD ? (t + 4) : (t - 5);
        tp = tp < 0 ? 0 : (tp > LL - 1 ? LL - 1 : tp);
        #pragma unroll
        for (int mt = 0; mt < 2; ++mt)
            up[SLOT][mt] = *(const float4*)(pu + (size_t)tp * TT + mt * 16);
    }
    Dacc += __builtin_amdgcn_logf(sprev);          // v_log_f32 = log2

    f32x4 s0v = ae0 + ao0;
    f32x4 s1v = ae1 + ao1;

    float rv[8];
    #pragma unroll
    for (int r = 0; r < 4; ++r) { rv[r] = ci * s0v[r]; rv[4 + r] = ci * s1v[r]; }

    if (!FWD) {
        bool cap = (cb == t - 1) && (cb != tfin);
        if (__any(cap)) {
            if (cap) {
                float4 c0 = {rv[0], rv[1], rv[2], rv[3]};
                float4 c1 = {rv[4], rv[5], rv[6], rv[7]};
                *(float4*)(rcap + rank * TT + wid * 32 + quad * 4) = c0;
                *(float4*)(rcap + rank * TT + wid * 32 + 16 + quad * 4) = c1;
                if (wid == 0 && quad == 0) drv[rank] = Dacc;
            }
        }
        bool inj = (tfin == t - 1);
        #pragma unroll
        for (int k = 0; k < 8; ++k) rv[k] = inj ? 1.0f : rv[k];
        Dacc = inj ? 0.0f : Dacc;
    }

    float ov[8];
    #pragma unroll
    for (int k = 0; k < 8; ++k) ov[k] = ex[k] * rv[k];

    if (FWD) {
        bool cap = (cb == t);
        if (__any(cap)) {
            if (cap) {
                float4 c0 = {ov[0], ov[1], ov[2], ov[3]};
                float4 c1 = {ov[4], ov[5], ov[6], ov[7]};
                *(float4*)(qcap + rank * TT + wid * 32 + quad * 4) = c0;
                *(float4*)(qcap + rank * TT + wid * 32 + 16 + quad * 4) = c1;
                if (wid == 0 && quad == 0) dqv[rank] = Dacc;
            }
        }
    }

    if (wid == 0 && quad == 0) sb[NXT * 16 + bl] = s0v[0];   // raw S0 (j=0)

    bfrw pk;
    pk.w[0] = pack2(ov[0], ov[1]);
    pk.w[1] = pack2(ov[2], ov[3]);
    pk.w[2] = pack2(ov[4], ov[5]);
    pk.w[3] = pack2(ov[6], ov[7]);
    *(bf16x8*)(qls + NXT * (16 * 136) + bl * 136 + (4 * wid + quad) * 8) = pk.v;

    lds_barrier();
}

__launch_bounds__(256, 1)
__global__ void crf_scan(const float* __restrict__ inputs,
                         const int*   __restrict__ tags,
                         const int*   __restrict__ slens,
                         const float* __restrict__ trans,
                         float* __restrict__ qcap, float* __restrict__ rcap,
                         float* __restrict__ dqv,  float* __restrict__ drv,
                         int* __restrict__ perm, float* __restrict__ scorebuf)
{
    __shared__ __align__(16) short qls[2 * 16 * 136];
    __shared__ float sb[2 * 16];
    __shared__ int keys[B_];

    const int tid  = threadIdx.x;

    // ---------------- score blocks (32..95): 4 batches each ----------------
    if (blockIdx.x >= 2 * NBLK) {
        const int sbid = blockIdx.x - 2 * NBLK;     // 0..63
        const int lane = tid & 63, wid = tid >> 6;
        #pragma unroll 1
        for (int bi = 0; bi < 4; ++bi) {
            const int b = sbid * 4 + bi;
            const int slen = slens[b];
            const float* inb  = inputs + (size_t)b * LL * TT;
            const int*   tagb = tags + b * LL;
            float sc = 0.f;
            for (int t = tid; t < slen; t += 256) {
                int tg = tagb[t];
                float v = inb[(size_t)t * TT + tg];
                if (t >= 1) v += trans[tagb[t - 1] * TT + tg];
                sc += v;
            }
            #pragma unroll
            for (int off = 32; off > 0; off >>= 1) sc += __shfl_xor(sc, off, 64);
            if (lane == 0) sb[wid] = sc;
            __syncthreads();
            if (tid == 0) scorebuf[b] = sb[0] + sb[1] + sb[2] + sb[3];
            __syncthreads();
        }
        return;
    }

    // ---------------- scan blocks (0..31) ----------------
    const int lane = tid & 63;
    const int wid  = __builtin_amdgcn_readfirstlane(tid >> 6);
    const int quad = lane >> 4;
    const int bl   = lane & 15;
    const bool isf = (blockIdx.x < NBLK);
    const int g    = isf ? blockIdx.x : blockIdx.x - NBLK;

    // deterministic bitonic sort of (slen, batch) keys — identical in all blocks
    keys[tid] = slens[tid] * 256 + tid;
    __syncthreads();
    for (int k = 2; k <= B_; k <<= 1) {
        for (int s = k >> 1; s > 0; s >>= 1) {
            int ixj = tid ^ s;
            if (ixj > tid) {
                int a = keys[tid], b2 = keys[ixj];
                bool asc = ((tid & k) == 0);
                if ((a > b2) == asc) { keys[tid] = b2; keys[ixj] = a; }
            }
            __syncthreads();
        }
    }
    if (isf && tid < 16) perm[g * 16 + tid] = keys[g * 16 + tid] & 255;

    const int key = keys[g * 16 + bl];
    const int ob  = key & 255;
    const int sl  = key >> 8;
    int tfin = sl - 1; if (tfin < 1) tfin = 1;

    int tmax = tfin;
    #pragma unroll
    for (int o = 1; o < 16; o <<= 1) {
        int c2 = __shfl_xor(tmax, o, 16); tmax = c2 > tmax ? c2 : tmax;
    }
    tmax = __builtin_amdgcn_readfirstlane(tmax);

    const int C  = (tmax + 4) >> 1;             // balanced cut (>=2)
    const int cb = tfin < C ? tfin : C;

    int cmax = cb, cmin = cb;
    #pragma unroll
    for (int o = 1; o < 16; o <<= 1) {
        int a = __shfl_xor(cmax, o, 16); cmax = a > cmax ? a : cmax;
        int b2 = __shfl_xor(cmin, o, 16); cmin = b2 < cmin ? b2 : cmin;
    }
    cmax = __builtin_amdgcn_readfirstlane(cmax);
    cmin = __builtin_amdgcn_readfirstlane(cmin);

    // A fragments with the segment k-permutation (round-6-verified):
    // k(c,quad,jj) = 32c + 16*(jj>>2) + 4*quad + (jj&3); j = wid*32+mt*16+bl
    bf16x8 af[2][4];
    #pragma unroll
    for (int mt = 0; mt < 2; ++mt) {
        const int j = wid * 32 + mt * 16 + bl;
        #pragma unroll
        for (int c = 0; c < 4; ++c) {
            #pragma unroll
            for (int jj = 0; jj < 8; ++jj) {
                int k = 32 * c + 16 * (jj >> 2) + 4 * quad + (jj & 3);
                int idx = isf ? (k * TT + j) : (j * TT + k);
                float ev = __builtin_amdgcn_exp2f(trans[idx] * L2E);
                af[mt][c][jj] = (short)(bfround(ev) >> 16);
            }
        }
    }

    const float* pu = inputs + (size_t)ob * LL * TT + wid * 32 + quad * 4;
    const int rank = g * 16 + bl;
    float Dacc = 0.f;
    float4 up[4][2];

    if (tid < 16) sb[tid] = 1.0f;

    if (isf) {
        // init q0 = exp(in[0][j]) -> qls buf0 (cb >= 1 always: no init capture)
        float q0[8];
        #pragma unroll
        for (int mt = 0; mt < 2; ++mt) {
            float4 v = *(const float4*)(pu + mt * 16);
            q0[4*mt+0] = __builtin_amdgcn_exp2f(v.x * L2E);
            q0[4*mt+1] = __builtin_amdgcn_exp2f(v.y * L2E);
            q0[4*mt+2] = __builtin_amdgcn_exp2f(v.z * L2E);
            q0[4*mt+3] = __builtin_amdgcn_exp2f(v.w * L2E);
        }
        bfrw pk;
        pk.w[0] = pack2(q0[0], q0[1]);
        pk.w[1] = pack2(q0[2], q0[3]);
        pk.w[2] = pack2(q0[4], q0[5]);
        pk.w[3] = pack2(q0[6], q0[7]);
        *(bf16x8*)(qls + bl * 136 + (4 * wid + quad) * 8) = pk.v;

        #pragma unroll
        for (int s = 1; s <= 4; ++s) {
            #pragma unroll
            for (int mt = 0; mt < 2; ++mt)
                up[s & 3][mt] = *(const float4*)(pu + (size_t)s * TT + mt * 16);
        }
        __syncthreads();

        for (int tb = 1; tb <= cmax; tb += 4) {
            phase<true,0>(tb+0, Dacc, up, af, qls, sb, pu, qcap, rcap, dqv, drv, cb, tfin, rank, wid, quad, bl);
            phase<true,1>(tb+1, Dacc, up, af, qls, sb, pu, qcap, rcap, dqv, drv, cb, tfin, rank, wid, quad, bl);
            phase<true,2>(tb+2, Dacc, up, af, qls, sb, pu, qcap, rcap, dqv, drv, cb, tfin, rank, wid, quad, bl);
            phase<true,3>(tb+3, Dacc, up, af, qls, sb, pu, qcap, rcap, dqv, drv, cb, tfin, rank, wid, quad, bl);
        }
    } else {
        // init w = 1.0; batches with cb == tfin capture ones / Dr = 0 here
        bfrw pk;
        pk.w[0] = pk.w[1] = pk.w[2] = pk.w[3] = 0x3F803F80u;
        *(bf16x8*)(qls + bl * 136 + (4 * wid + quad) * 8) = pk.v;
        if (cb == tfin) {
            float4 one4 = {1.f, 1.f, 1.f, 1.f};
            *(float4*)(rcap + rank * TT + wid * 32 + quad * 4) = one4;
            *(float4*)(rcap + rank * TT + wid * 32 + 16 + quad * 4) = one4;
            if (wid == 0 && quad == 0) drv[rank] = 0.f;
        }

        const int tb0 = (tmax + 4) & ~3;   // >= tmax+1, == 0 mod 4
        #pragma unroll
        for (int ph = 0; ph < 4; ++ph) {
            int ui = tb0 - 1 - ph;
            ui = ui > LL - 1 ? LL - 1 : (ui < 0 ? 0 : ui);
            #pragma unroll
            for (int mt = 0; mt < 2; ++mt)
                up[(3 - ph) & 3][mt] = *(const float4*)(pu + (size_t)ui * TT + mt * 16);
        }
        __syncthreads();

        for (int tb = tb0; tb > cmin; tb -= 4) {
            phase<false,0>(tb-0, Dacc, up, af, qls, sb, pu, qcap, rcap, dqv, drv, cb, tfin, rank, wid, quad, bl);
            phase<false,1>(tb-1, Dacc, up, af, qls, sb, pu, qcap, rcap, dqv, drv, cb, tfin, rank, wid, quad, bl);
            phase<false,2>(tb-2, Dacc, up, af, qls, sb, pu, qcap, rcap, dqv, drv, cb, tfin, rank, wid, quad, bl);
            phase<false,3>(tb-3, Dacc, up, af, qls, sb, pu, qcap, rcap, dqv, drv, cb, tfin, rank, wid, quad, bl);
        }
    }
}

__global__ void crf_comb(const float* __restrict__ qcap, const float* __restrict__ rcap,
                         const float* __restrict__ dqv, const float* __restrict__ drv,
                         const int* __restrict__ perm, const float* __restrict__ scorebuf,
                         float* __restrict__ out) {
    const int tid = threadIdx.x;
    const int r16 = tid >> 4, part = tid & 15;
    const int rank = blockIdx.x * 16 + r16;
    const float* qc = qcap + rank * TT + part * 8;
    const float* rc = rcap + rank * TT + part * 8;
    float4 a0 = *(const float4*)(qc);
    float4 a1 = *(const float4*)(qc + 4);
    float4 b0 = *(const float4*)(rc);
    float4 b1 = *(const float4*)(rc + 4);
    float s = a0.x*b0.x + a0.y*b0.y + a0.z*b0.z + a0.w*b0.w
            + a1.x*b1.x + a1.y*b1.y + a1.z*b1.z + a1.w*b1.w;
    #pragma unroll
    for (int o = 1; o < 16; o <<= 1) s += __shfl_xor(s, o, 16);
    if (part == 0) {
        int ob = perm[rank];
        float logZ = LN2f * (__builtin_amdgcn_logf(s) + dqv[rank] + drv[rank]);
        out[ob] = scorebuf[ob] - logZ;
    }
}

extern "C" void kernel_launch(void* const* d_in, const int* in_sizes, int n_in,
                              void* d_out, int out_size, void* d_ws, size_t ws_size,
                              hipStream_t stream) {
    const float* inputs = (const float*)d_in[0];
    const int*   tags   = (const int*)d_in[1];
    const int*   slens  = (const int*)d_in[2];
    const float* trans  = (const float*)d_in[3];
    float* out = (float*)d_out;

    float* qcap = (float*)d_ws;            // 256*128 f32
    float* rcap = qcap + 32768;            // 256*128 f32
    float* dqv  = rcap + 32768;            // 256
    float* drv  = dqv + 256;               // 256
    int*   perm = (int*)(drv + 256);       // 256
    float* scorebuf = (float*)(perm + 256);// 256

    crf_scan<<<2 * NBLK + 64, 256, 0, stream>>>(inputs, tags, slens, trans,
                                                qcap, rcap, dqv, drv, perm, scorebuf);
    crf_comb<<<NBLK, 256, 0, stream>>>(qcap, rcap, dqv, drv, perm, scorebuf, out);
}